// Round 7
// baseline (45.871 us; speedup 1.0000x reference)
//
#include <hip/hip_runtime.h>

namespace {

typedef __attribute__((ext_vector_type(8))) short short8;  // 8 bf16 = 4 VGPR
typedef __attribute__((ext_vector_type(4))) float f32x4;   // MFMA accumulator

constexpr int kNB = 256;   // batch
constexpr int kNQ = 16;    // queries per batch
constexpr int kNK = 200;   // keys per batch
constexpr int kDK = 64;    // key/query feature size
constexpr int kNH = 128;   // hidden
constexpr float kNeg = -1000000000.0f;
constexpr float kC2 = 2.8853900817779268f;  // 2*log2(e): exp(2x)=exp2(kC2*x)

// ---- kernel1 geometry: one block = (batch, h-half of 64) ----
constexpr int kS1 = 66;  // Ek row stride (floats) in the half-h LDS tile
constexpr size_t kWsNeed = (size_t)kNB * 2 * kNQ * kNK * sizeof(float);  // 6.55 MB

__device__ __forceinline__ float exp2_hw(float x) {
#if defined(__has_builtin)
# if __has_builtin(__builtin_amdgcn_exp2f)
  return __builtin_amdgcn_exp2f(x);
# else
  return __expf(x * 0.69314718055994531f);
# endif
#else
  return __expf(x * 0.69314718055994531f);
#endif
}

template <int CTRL>
__device__ __forceinline__ float dpp_add(float v) {
  int sw = __builtin_amdgcn_update_dpp(0, __float_as_int(v), CTRL, 0xF, 0xF, true);
  return v + __int_as_float(sw);
}

// ---- split-bf16 helpers (round-to-nearest-even) ----
__device__ __forceinline__ short bf_hi(float x) {
  unsigned u = __float_as_uint(x);
  return (short)((u + 0x7FFFu + ((u >> 16) & 1u)) >> 16);
}
__device__ __forceinline__ float bf_f(short s) {
  return __uint_as_float(((unsigned)(unsigned short)s) << 16);
}
__device__ __forceinline__ void split8(float4 a, float4 b, short8& hi, short8& lo) {
  float v[8] = {a.x, a.y, a.z, a.w, b.x, b.y, b.z, b.w};
#pragma unroll
  for (int j = 0; j < 8; ++j) {
    const short h = bf_hi(v[j]);
    hi[j] = h;
    lo[j] = bf_hi(v[j] - bf_f(h));
  }
}

// =====================================================================
// Kernel 1: project kh/qh half (MFMA, split-bf16) -> Ek/Eq in LDS ->
// partial scores over this block's 64 h -> d_ws. 2 blocks/CU.
// =====================================================================
__launch_bounds__(512)
__attribute__((amdgpu_waves_per_eu(4, 4)))
__global__ void proj_score(const float* __restrict__ queries,
                           const float* __restrict__ keys,
                           const float* __restrict__ Wq,
                           const float* __restrict__ bq,
                           const float* __restrict__ Wk,
                           const float* __restrict__ bk,
                           const float* __restrict__ Wv,
                           float* __restrict__ ps) {
  __shared__ float skh[kNK * kS1];  // Ek = exp2(kC2*kh), this h-half  (52.8 KB)
  __shared__ float sqh[kNQ * kS1];  // Eq                              ( 4.2 KB)

  const int tid  = threadIdx.x;
  const int b    = blockIdx.x >> 1;
  const int hb   = blockIdx.x & 1;   // h-half: cols hb*64 .. +63
  const int lane = tid & 63;
  const int wave = __builtin_amdgcn_readfirstlane(tid >> 6);  // 0..7
  const int l15  = lane & 15;
  const int q16  = lane >> 4;

  const float* kb = keys + (size_t)b * kNK * kDK;
  const float* qb = queries + (size_t)b * kNQ * kDK;

  // ---- projection: 4 col-tiles (this half) x 13 row-tiles + 4 query tiles ----
  {
    const int tc   = wave >> 1;       // col-tile 0..3
    const int odd  = wave & 1;
    const int lcol = tc * 16 + l15;   // local col 0..63
    const int gcol = hb * 64 + lcol;  // global h
    const int kj0  = q16 * 8;         // A/B k-base for this lane

    short8 bh[2], bl[2];              // Wk col-slice fragments, once per wave
#pragma unroll
    for (int p = 0; p < 2; ++p) {
      float4 v0, v1;
      v0.x = Wk[(p * 32 + kj0 + 0) * kNH + gcol];
      v0.y = Wk[(p * 32 + kj0 + 1) * kNH + gcol];
      v0.z = Wk[(p * 32 + kj0 + 2) * kNH + gcol];
      v0.w = Wk[(p * 32 + kj0 + 3) * kNH + gcol];
      v1.x = Wk[(p * 32 + kj0 + 4) * kNH + gcol];
      v1.y = Wk[(p * 32 + kj0 + 5) * kNH + gcol];
      v1.z = Wk[(p * 32 + kj0 + 6) * kNH + gcol];
      v1.w = Wk[(p * 32 + kj0 + 7) * kNH + gcol];
      split8(v0, v1, bh[p], bl[p]);
    }
    const float bkc = bk[gcol];

    const int trB = odd ? 7 : 0;
    const int trE = odd ? 13 : 7;  // even: 7 row-tiles; odd: 6 + query tile
    for (int tr = trB; tr < trE; ++tr) {
      f32x4 acc = {0.f, 0.f, 0.f, 0.f};
      const int row = tr * 16 + l15;
      const bool ok = row < kNK;
#pragma unroll
      for (int p = 0; p < 2; ++p) {
        float4 a0 = {0.f, 0.f, 0.f, 0.f}, a1 = {0.f, 0.f, 0.f, 0.f};
        if (ok) {
          const float* ap = kb + (size_t)row * kDK + p * 32 + kj0;
          a0 = *reinterpret_cast<const float4*>(ap);
          a1 = *reinterpret_cast<const float4*>(ap + 4);
        }
        short8 ah, al;
        split8(a0, a1, ah, al);
        acc = __builtin_amdgcn_mfma_f32_16x16x32_bf16(al, bh[p], acc, 0, 0, 0);
        acc = __builtin_amdgcn_mfma_f32_16x16x32_bf16(ah, bl[p], acc, 0, 0, 0);
        acc = __builtin_amdgcn_mfma_f32_16x16x32_bf16(ah, bh[p], acc, 0, 0, 0);
      }
#pragma unroll
      for (int r = 0; r < 4; ++r) {
        const int rr = tr * 16 + q16 * 4 + r;  // C row = (lane>>4)*4 + reg
        if (rr < kNK) skh[rr * kS1 + lcol] = exp2_hw(kC2 * (acc[r] + bkc));
      }
    }

    if (odd) {  // query tile (16 rows) for col-tile tc
      short8 qbh[2], qbl[2];
#pragma unroll
      for (int p = 0; p < 2; ++p) {
        float4 v0, v1;
        v0.x = Wq[(p * 32 + kj0 + 0) * kNH + gcol];
        v0.y = Wq[(p * 32 + kj0 + 1) * kNH + gcol];
        v0.z = Wq[(p * 32 + kj0 + 2) * kNH + gcol];
        v0.w = Wq[(p * 32 + kj0 + 3) * kNH + gcol];
        v1.x = Wq[(p * 32 + kj0 + 4) * kNH + gcol];
        v1.y = Wq[(p * 32 + kj0 + 5) * kNH + gcol];
        v1.z = Wq[(p * 32 + kj0 + 6) * kNH + gcol];
        v1.w = Wq[(p * 32 + kj0 + 7) * kNH + gcol];
        split8(v0, v1, qbh[p], qbl[p]);
      }
      const float bqc = bq[gcol];
      f32x4 acc = {0.f, 0.f, 0.f, 0.f};
#pragma unroll
      for (int p = 0; p < 2; ++p) {
        const float* ap = qb + (size_t)l15 * kDK + p * 32 + kj0;
        const float4 a0 = *reinterpret_cast<const float4*>(ap);
        const float4 a1 = *reinterpret_cast<const float4*>(ap + 4);
        short8 ah, al;
        split8(a0, a1, ah, al);
        acc = __builtin_amdgcn_mfma_f32_16x16x32_bf16(al, qbh[p], acc, 0, 0, 0);
        acc = __builtin_amdgcn_mfma_f32_16x16x32_bf16(ah, qbl[p], acc, 0, 0, 0);
        acc = __builtin_amdgcn_mfma_f32_16x16x32_bf16(ah, qbh[p], acc, 0, 0, 0);
      }
#pragma unroll
      for (int r = 0; r < 4; ++r)
        sqh[(q16 * 4 + r) * kS1 + lcol] = exp2_hw(kC2 * (acc[r] + bqc));
    }
  }

  // per-lane Wv slice: 4 h per lane (16-lane groups cover the 64-col half)
  float wv2[4];
  {
    const float4 w4 = *reinterpret_cast<const float4*>(&Wv[hb * 64 + 4 * l15]);
    wv2[0] = -2.0f * w4.x; wv2[1] = -2.0f * w4.y;
    wv2[2] = -2.0f * w4.z; wv2[3] = -2.0f * w4.w;
  }

  __syncthreads();  // Ek/Eq visible (the only barrier in this kernel)

  // ---- partial scores: wave (qg,kg) -> queries 4qg..4qg+3, k = 8i+4kg+q16 ----
  const int qg = wave >> 1;
  const int kg = wave & 1;
  float qreg[4][4];
#pragma unroll
  for (int qi = 0; qi < 4; ++qi) {
    const float4 q4 = *reinterpret_cast<const float4*>(&sqh[(4 * qg + qi) * kS1 + 4 * l15]);
    qreg[qi][0] = q4.x; qreg[qi][1] = q4.y; qreg[qi][2] = q4.z; qreg[qi][3] = q4.w;
  }
#pragma unroll
  for (int qi = 0; qi < 4; ++qi)
#pragma unroll
    for (int m = 0; m < 4; ++m) asm volatile("" : "+v"(qreg[qi][m]));

  float* pw = ps + ((size_t)(b * 2 + hb) * kNQ) * kNK;
  for (int i = 0; i < 25; ++i) {
    const int k = 8 * i + 4 * kg + q16;
    const float4 ek = *reinterpret_cast<const float4*>(&skh[k * kS1 + 4 * l15]);
#pragma unroll
    for (int qi = 0; qi < 4; ++qi) {
      const float e0 = qreg[qi][0] * ek.x;
      const float e1 = qreg[qi][1] * ek.y;
      const float e2 = qreg[qi][2] * ek.z;
      const float e3 = qreg[qi][3] * ek.w;
      const float r0 = __builtin_amdgcn_rcpf(1.0f + e0);
      const float r1 = __builtin_amdgcn_rcpf(1.0f + e1);
      const float r2 = __builtin_amdgcn_rcpf(1.0f + e2);
      const float r3 = __builtin_amdgcn_rcpf(1.0f + e3);
      float acc = wv2[0] * r0;
      acc = fmaf(wv2[1], r1, acc);
      acc = fmaf(wv2[2], r2, acc);
      acc = fmaf(wv2[3], r3, acc);
      acc = dpp_add<0xB1>(acc);   // xor 1
      acc = dpp_add<0x4E>(acc);   // xor 2
      acc = dpp_add<0x141>(acc);  // row_half_mirror (8-fold)
      acc = dpp_add<0x140>(acc);  // row_mirror (16-fold)
      if (l15 == 0) pw[(4 * qg + qi) * kNK + k] = acc;  // partial over 64 h
    }
  }
}

// =====================================================================
// Kernel 2: sum h-half partials -> mask -> softmax -> out_w; split-k
// GEMV epilogue -> out_attn. Grid 256 x 1024, small LDS.
// =====================================================================
__launch_bounds__(1024)
__global__ void softmax_gemv(const float* __restrict__ keys,
                             const float* __restrict__ masks,
                             const float* __restrict__ ps,
                             float* __restrict__ out_attn,
                             float* __restrict__ out_w) {
  __shared__ float sw[kNQ * kNK];      // weights (12.8 KB)
  __shared__ float pk[kNQ * 4 * kDK];  // GEMV partials (16 KB)

  const int tid  = threadIdx.x;
  const int b    = blockIdx.x;
  const int lane = tid & 63;
  const int wave = __builtin_amdgcn_readfirstlane(tid >> 6);  // 0..15 == query row

  const float* kb = keys + (size_t)b * kNK * kDK;

  // ---- combine halves + mask + softmax (wave w owns query row w) ----
  {
    const float* p0 = ps + ((size_t)(b * 2 + 0) * kNQ + wave) * kNK;
    const float* p1 = ps + ((size_t)(b * 2 + 1) * kNQ + wave) * kNK;
    const float* mrow = masks + ((size_t)b * kNQ + wave) * kNK;
    const bool tail = lane < (kNK - 192);
    float v0 = fmaf(mrow[lane],       kNeg, p0[lane]       + p1[lane]);
    float v1 = fmaf(mrow[lane + 64],  kNeg, p0[lane + 64]  + p1[lane + 64]);
    float v2 = fmaf(mrow[lane + 128], kNeg, p0[lane + 128] + p1[lane + 128]);
    float v3 = tail ? fmaf(mrow[lane + 192], kNeg, p0[lane + 192] + p1[lane + 192])
                    : -1e30f;
    float m = fmaxf(fmaxf(v0, v1), fmaxf(v2, v3));
#pragma unroll
    for (int off = 32; off > 0; off >>= 1) m = fmaxf(m, __shfl_xor(m, off, 64));
    const float e0 = __expf(v0 - m);
    const float e1 = __expf(v1 - m);
    const float e2 = __expf(v2 - m);
    const float e3 = tail ? __expf(v3 - m) : 0.f;
    float sum = (e0 + e1) + (e2 + e3);
#pragma unroll
    for (int off = 32; off > 0; off >>= 1) sum += __shfl_xor(sum, off, 64);
    const float rs = __builtin_amdgcn_rcpf(sum);
    float* og = out_w + ((size_t)b * kNQ + wave) * kNK;
    float* swr = &sw[wave * kNK];
    const float w0 = e0 * rs, w1 = e1 * rs, w2 = e2 * rs, w3 = e3 * rs;
    swr[lane]       = w0;  og[lane]       = w0;
    swr[lane + 64]  = w1;  og[lane + 64]  = w1;
    swr[lane + 128] = w2;  og[lane + 128] = w2;
    if (tail) { swr[lane + 192] = w3; og[lane + 192] = w3; }
  }
  __syncthreads();

  // ---- epilogue: wave (qg,kg) partial GEMV over its k-range ----
  {
    const int qg = wave >> 2;
    const int kg = wave & 3;
    const int kstart = 52 * kg;
    const int kend = (kg == 3) ? kNK : (kstart + 52);
    const float* kb2 = kb + lane;  // d = lane
    float acc[4] = {0.f, 0.f, 0.f, 0.f};
    for (int k0 = kstart; k0 < kend; k0 += 4) {
      const float kv0 = kb2[(size_t)(k0 + 0) * kDK];
      const float kv1 = kb2[(size_t)(k0 + 1) * kDK];
      const float kv2 = kb2[(size_t)(k0 + 2) * kDK];
      const float kv3 = kb2[(size_t)(k0 + 3) * kDK];
#pragma unroll
      for (int qi = 0; qi < 4; ++qi) {
        const float4 wq = *reinterpret_cast<const float4*>(&sw[(4 * qg + qi) * kNK + k0]);
        acc[qi] = fmaf(wq.x, kv0, acc[qi]);
        acc[qi] = fmaf(wq.y, kv1, acc[qi]);
        acc[qi] = fmaf(wq.z, kv2, acc[qi]);
        acc[qi] = fmaf(wq.w, kv3, acc[qi]);
      }
    }
#pragma unroll
    for (int qi = 0; qi < 4; ++qi)
      pk[((4 * qg + qi) * 4 + kg) * kDK + lane] = acc[qi];
  }
  __syncthreads();

  // ---- final combine: wave w sums 4 partials of query w ----
  {
    const float r = pk[(wave * 4 + 0) * kDK + lane] + pk[(wave * 4 + 1) * kDK + lane] +
                    pk[(wave * 4 + 2) * kDK + lane] + pk[(wave * 4 + 3) * kDK + lane];
    out_attn[((size_t)b * kNQ + wave) * kDK + lane] = r;
  }
}

// =====================================================================
// Fallback monolith (R6) — used only if ws_size is too small.
// =====================================================================
constexpr int kThreads = 1024;
constexpr int kS = 132;
constexpr int kKhFloats = kNK * kS;
constexpr int kScFloats = kNQ * kNK;
constexpr int kQhFloats = kNQ * kNH;
constexpr size_t kSmemBytes =
    (size_t)(kKhFloats + kScFloats + kQhFloats) * sizeof(float);

__launch_bounds__(kThreads)
__attribute__((amdgpu_waves_per_eu(4, 4)))
__global__ void bahdanau_fused(const float* __restrict__ queries,
                               const float* __restrict__ keys,
                               const float* __restrict__ masks,
                               const float* __restrict__ Wq,
                               const float* __restrict__ bq,
                               const float* __restrict__ Wk,
                               const float* __restrict__ bk,
                               const float* __restrict__ Wv,
                               float* __restrict__ out_attn,
                               float* __restrict__ out_w) {
  extern __shared__ __align__(16) float smem[];
  float* skh = smem;
  float* ssc = smem + kKhFloats;
  float* sqh = smem + kKhFloats + kScFloats;

  const int tid  = threadIdx.x;
  const int b    = blockIdx.x;
  const int lane = tid & 63;
  const int wave = __builtin_amdgcn_readfirstlane(tid >> 6);
  const int l15  = lane & 15;
  const int q16  = lane >> 4;
  const int hbase = 8 * l15;

  const float* kb = keys + (size_t)b * kNK * kDK;
  const float* qb = queries + (size_t)b * kNQ * kDK;

  {
    const int tc  = wave >> 1;
    const int odd = wave & 1;
    const int col = tc * 16 + l15;
    const int kj0 = q16 * 8;

    short8 bh[2], bl[2];
#pragma unroll
    for (int p = 0; p < 2; ++p) {
      float4 v0, v1;
      v0.x = Wk[(p * 32 + kj0 + 0) * kNH + col];
      v0.y = Wk[(p * 32 + kj0 + 1) * kNH + col];
      v0.z = Wk[(p * 32 + kj0 + 2) * kNH + col];
      v0.w = Wk[(p * 32 + kj0 + 3) * kNH + col];
      v1.x = Wk[(p * 32 + kj0 + 4) * kNH + col];
      v1.y = Wk[(p * 32 + kj0 + 5) * kNH + col];
      v1.z = Wk[(p * 32 + kj0 + 6) * kNH + col];
      v1.w = Wk[(p * 32 + kj0 + 7) * kNH + col];
      split8(v0, v1, bh[p], bl[p]);
    }
    const float bkc = bk[col];
    const int trB = odd ? 7 : 0;
    const int trE = odd ? 13 : 7;
    for (int tr = trB; tr < trE; ++tr) {
      f32x4 acc = {0.f, 0.f, 0.f, 0.f};
      const int row = tr * 16 + l15;
      const bool ok = row < kNK;
#pragma unroll
      for (int p = 0; p < 2; ++p) {
        float4 a0 = {0.f, 0.f, 0.f, 0.f}, a1 = {0.f, 0.f, 0.f, 0.f};
        if (ok) {
          const float* ap = kb + (size_t)row * kDK + p * 32 + kj0;
          a0 = *reinterpret_cast<const float4*>(ap);
          a1 = *reinterpret_cast<const float4*>(ap + 4);
        }
        short8 ah, al;
        split8(a0, a1, ah, al);
        acc = __builtin_amdgcn_mfma_f32_16x16x32_bf16(al, bh[p], acc, 0, 0, 0);
        acc = __builtin_amdgcn_mfma_f32_16x16x32_bf16(ah, bl[p], acc, 0, 0, 0);
        acc = __builtin_amdgcn_mfma_f32_16x16x32_bf16(ah, bh[p], acc, 0, 0, 0);
      }
#pragma unroll
      for (int r = 0; r < 4; ++r) {
        const int rr = tr * 16 + q16 * 4 + r;
        if (rr < kNK) skh[(size_t)rr * kS + col] = exp2_hw(kC2 * (acc[r] + bkc));
      }
    }
    if (odd) {
      short8 qbh[2], qbl[2];
#pragma unroll
      for (int p = 0; p < 2; ++p) {
        float4 v0, v1;
        v0.x = Wq[(p * 32 + kj0 + 0) * kNH + col];
        v0.y = Wq[(p * 32 + kj0 + 1) * kNH + col];
        v0.z = Wq[(p * 32 + kj0 + 2) * kNH + col];
        v0.w = Wq[(p * 32 + kj0 + 3) * kNH + col];
        v1.x = Wq[(p * 32 + kj0 + 4) * kNH + col];
        v1.y = Wq[(p * 32 + kj0 + 5) * kNH + col];
        v1.z = Wq[(p * 32 + kj0 + 6) * kNH + col];
        v1.w = Wq[(p * 32 + kj0 + 7) * kNH + col];
        split8(v0, v1, qbh[p], qbl[p]);
      }
      const float bqc = bq[col];
      f32x4 acc = {0.f, 0.f, 0.f, 0.f};
#pragma unroll
      for (int p = 0; p < 2; ++p) {
        const float* ap = qb + (size_t)l15 * kDK + p * 32 + kj0;
        const float4 a0 = *reinterpret_cast<const float4*>(ap);
        const float4 a1 = *reinterpret_cast<const float4*>(ap + 4);
        short8 ah, al;
        split8(a0, a1, ah, al);
        acc = __builtin_amdgcn_mfma_f32_16x16x32_bf16(al, qbh[p], acc, 0, 0, 0);
        acc = __builtin_amdgcn_mfma_f32_16x16x32_bf16(ah, qbl[p], acc, 0, 0, 0);
        acc = __builtin_amdgcn_mfma_f32_16x16x32_bf16(ah, qbh[p], acc, 0, 0, 0);
      }
#pragma unroll
      for (int r = 0; r < 4; ++r)
        sqh[(size_t)(q16 * 4 + r) * kNH + col] = exp2_hw(kC2 * (acc[r] + bqc));
    }
  }

  float wv2[8];
  {
    const float4 wva = *reinterpret_cast<const float4*>(&Wv[hbase]);
    const float4 wvb = *reinterpret_cast<const float4*>(&Wv[hbase + 4]);
    wv2[0] = -2.0f * wva.x; wv2[1] = -2.0f * wva.y;
    wv2[2] = -2.0f * wva.z; wv2[3] = -2.0f * wva.w;
    wv2[4] = -2.0f * wvb.x; wv2[5] = -2.0f * wvb.y;
    wv2[6] = -2.0f * wvb.z; wv2[7] = -2.0f * wvb.w;
  }

  __syncthreads();

  const int qg = wave >> 2;
  const int kg = wave & 3;
  float qreg[4][8];
#pragma unroll
  for (int qi = 0; qi < 4; ++qi) {
    const float4 qa  = *reinterpret_cast<const float4*>(&sqh[(4 * qg + qi) * kNH + hbase]);
    const float4 qb4 = *reinterpret_cast<const float4*>(&sqh[(4 * qg + qi) * kNH + hbase + 4]);
    qreg[qi][0] = qa.x;  qreg[qi][1] = qa.y;  qreg[qi][2] = qa.z;  qreg[qi][3] = qa.w;
    qreg[qi][4] = qb4.x; qreg[qi][5] = qb4.y; qreg[qi][6] = qb4.z; qreg[qi][7] = qb4.w;
  }

  {
    auto score_k = [&](int k) {
      const float* krow = &skh[(size_t)k * kS + hbase];
      const float4 ka  = *reinterpret_cast<const float4*>(krow);
      const float4 kb4 = *reinterpret_cast<const float4*>(krow + 4);
#pragma unroll
      for (int qi = 0; qi < 4; ++qi) {
        const float e0 = qreg[qi][0] * ka.x;
        const float e1 = qreg[qi][1] * ka.y;
        const float e2 = qreg[qi][2] * ka.z;
        const float e3 = qreg[qi][3] * ka.w;
        const float e4 = qreg[qi][4] * kb4.x;
        const float e5 = qreg[qi][5] * kb4.y;
        const float e6 = qreg[qi][6] * kb4.z;
        const float e7 = qreg[qi][7] * kb4.w;
        const float r0 = __builtin_amdgcn_rcpf(1.0f + e0);
        const float r1 = __builtin_amdgcn_rcpf(1.0f + e1);
        const float r2 = __builtin_amdgcn_rcpf(1.0f + e2);
        const float r3 = __builtin_amdgcn_rcpf(1.0f + e3);
        const float r4 = __builtin_amdgcn_rcpf(1.0f + e4);
        const float r5 = __builtin_amdgcn_rcpf(1.0f + e5);
        const float r6 = __builtin_amdgcn_rcpf(1.0f + e6);
        const float r7 = __builtin_amdgcn_rcpf(1.0f + e7);
        float acc0 = wv2[0] * r0;
        acc0 = fmaf(wv2[1], r1, acc0);
        acc0 = fmaf(wv2[2], r2, acc0);
        acc0 = fmaf(wv2[3], r3, acc0);
        float acc1 = wv2[4] * r4;
        acc1 = fmaf(wv2[5], r5, acc1);
        acc1 = fmaf(wv2[6], r6, acc1);
        acc1 = fmaf(wv2[7], r7, acc1);
        float acc = acc0 + acc1;
        acc = dpp_add<0xB1>(acc);
        acc = dpp_add<0x4E>(acc);
        acc = dpp_add<0x141>(acc);
        acc = dpp_add<0x140>(acc);
        if (l15 == 0) ssc[(4 * qg + qi) * kNK + k] = acc;
      }
    };
    for (int i = 0; i < 12; ++i) score_k(16 * i + 4 * kg + q16);
    if (kg < 2) score_k(192 + 4 * kg + q16);
  }

  const float* mrow = masks + ((size_t)b * kNQ + wave) * kNK;
  const bool tail = lane < (kNK - 192);
  const float mm0 = mrow[lane];
  const float mm1 = mrow[lane + 64];
  const float mm2 = mrow[lane + 128];
  const float mm3 = tail ? mrow[lane + 192] : 0.0f;

  __syncthreads();

  {
    const float* sr = &ssc[wave * kNK];
    float v0 = fmaf(mm0, kNeg, sr[lane]);
    float v1 = fmaf(mm1, kNeg, sr[lane + 64]);
    float v2 = fmaf(mm2, kNeg, sr[lane + 128]);
    float v3 = tail ? fmaf(mm3, kNeg, sr[lane + 192]) : -1e30f;
    float m = fmaxf(fmaxf(v0, v1), fmaxf(v2, v3));
#pragma unroll
    for (int off = 32; off > 0; off >>= 1) m = fmaxf(m, __shfl_xor(m, off, 64));
    const float e0 = __expf(v0 - m);
    const float e1 = __expf(v1 - m);
    const float e2 = __expf(v2 - m);
    const float e3 = tail ? __expf(v3 - m) : 0.f;
    float sum = (e0 + e1) + (e2 + e3);
#pragma unroll
    for (int off = 32; off > 0; off >>= 1) sum += __shfl_xor(sum, off, 64);
    const float rs = __builtin_amdgcn_rcpf(sum);
    float* og = out_w + ((size_t)b * kNQ + wave) * kNK;
    float* swr = &ssc[wave * kNK];
    const float w0 = e0 * rs, w1 = e1 * rs, w2 = e2 * rs, w3 = e3 * rs;
    swr[lane]       = w0;  og[lane]       = w0;
    swr[lane + 64]  = w1;  og[lane + 64]  = w1;
    swr[lane + 128] = w2;  og[lane + 128] = w2;
    if (tail) { swr[lane + 192] = w3; og[lane + 192] = w3; }
  }
  __syncthreads();

  {
    float* pk = skh;
    const int kstart = 52 * kg;
    const int kend = (kg == 3) ? kNK : (kstart + 52);
    const float* kb2 = kb + lane;
    float acc[4] = {0.f, 0.f, 0.f, 0.f};
    for (int k0 = kstart; k0 < kend; k0 += 4) {
      const float kv0 = kb2[(size_t)(k0 + 0) * kDK];
      const float kv1 = kb2[(size_t)(k0 + 1) * kDK];
      const float kv2 = kb2[(size_t)(k0 + 2) * kDK];
      const float kv3 = kb2[(size_t)(k0 + 3) * kDK];
#pragma unroll
      for (int qi = 0; qi < 4; ++qi) {
        const float4 wq = *reinterpret_cast<const float4*>(&ssc[(4 * qg + qi) * kNK + k0]);
        acc[qi] = fmaf(wq.x, kv0, acc[qi]);
        acc[qi] = fmaf(wq.y, kv1, acc[qi]);
        acc[qi] = fmaf(wq.z, kv2, acc[qi]);
        acc[qi] = fmaf(wq.w, kv3, acc[qi]);
      }
    }
#pragma unroll
    for (int qi = 0; qi < 4; ++qi)
      pk[((4 * qg + qi) * 4 + kg) * kDK + lane] = acc[qi];
  }
  __syncthreads();

  {
    const float* pk = skh;
    const float r = pk[(wave * 4 + 0) * kDK + lane] + pk[(wave * 4 + 1) * kDK + lane] +
                    pk[(wave * 4 + 2) * kDK + lane] + pk[(wave * 4 + 3) * kDK + lane];
    out_attn[((size_t)b * kNQ + wave) * kDK + lane] = r;
  }
}

}  // namespace

extern "C" void kernel_launch(void* const* d_in, const int* in_sizes, int n_in,
                              void* d_out, int out_size, void* d_ws, size_t ws_size,
                              hipStream_t stream) {
  const float* queries = (const float*)d_in[0];
  const float* keys    = (const float*)d_in[1];
  const float* masks   = (const float*)d_in[2];
  // d_in[3] = num_neg (unused)
  const float* Wq = (const float*)d_in[4];
  const float* bq = (const float*)d_in[5];
  const float* Wk = (const float*)d_in[6];
  const float* bk = (const float*)d_in[7];
  const float* Wv = (const float*)d_in[8];
  // d_in[9] = bv: softmax-invariant, dropped

  float* out_attn = (float*)d_out;                       // (B, NQ, 64)
  float* out_w    = out_attn + (size_t)kNB * kNQ * kDK;  // (B, NQ, 200, 1)

  if (ws_size >= kWsNeed) {
    float* ps = (float*)d_ws;  // (B, 2, NQ, NK) partial scores
    proj_score<<<kNB * 2, 512, 0, stream>>>(queries, keys, Wq, bq, Wk, bk, Wv, ps);
    softmax_gemv<<<kNB, 1024, 0, stream>>>(keys, masks, ps, out_attn, out_w);
  } else {
    hipFuncSetAttribute((const void*)bahdanau_fused,
                        hipFuncAttributeMaxDynamicSharedMemorySize, (int)kSmemBytes);
    bahdanau_fused<<<kNB, kThreads, kSmemBytes, stream>>>(queries, keys, masks, Wq, bq,
                                                          Wk, bk, Wv, out_attn, out_w);
  }
}

// Round 8
// 42.819 us; speedup vs baseline: 1.0713x; 1.0713x over previous
//
#include <hip/hip_runtime.h>
#include <hip/hip_bf16.h>

namespace {

typedef __attribute__((ext_vector_type(8))) short short8;  // 8 bf16 = 4 VGPR
typedef __attribute__((ext_vector_type(4))) float f32x4;   // MFMA accumulator

constexpr int kNB = 256;   // batch
constexpr int kNQ = 16;    // queries per batch
constexpr int kNK = 200;   // keys per batch
constexpr int kDK = 64;    // key/query feature size
constexpr int kNH = 128;   // hidden
constexpr int kHK = 100;   // keys per k-half block
constexpr int kS  = 132;   // Ek row stride in floats (132 mod 32 = 4: spread banks)
constexpr float kNeg = -1000000000.0f;
constexpr float kC2 = 2.8853900817779268f;  // 2*log2(e): exp(2x)=exp2(kC2*x)

constexpr size_t kWsNeed = (size_t)kNB * kNQ * kNK * sizeof(float);  // 3.28 MB

__device__ __forceinline__ float exp2_hw(float x) {
#if defined(__has_builtin)
# if __has_builtin(__builtin_amdgcn_exp2f)
  return __builtin_amdgcn_exp2f(x);
# else
  return __expf(x * 0.69314718055994531f);
# endif
#else
  return __expf(x * 0.69314718055994531f);
#endif
}

template <int CTRL>
__device__ __forceinline__ float dpp_add(float v) {
  int sw = __builtin_amdgcn_update_dpp(0, __float_as_int(v), CTRL, 0xF, 0xF, true);
  return v + __int_as_float(sw);
}

// split-bf16 via hip casts: compiler packs v_cvt_pk_bf16_f32 (fewer VALU ops
// than manual round-nearest bit twiddling).
__device__ __forceinline__ void split8(float4 a, float4 b, short8& hi, short8& lo) {
  float v[8] = {a.x, a.y, a.z, a.w, b.x, b.y, b.z, b.w};
#pragma unroll
  for (int j = 0; j < 8; ++j) {
    const __hip_bfloat16 h = __float2bfloat16(v[j]);
    hi[j] = (short)__bfloat16_as_ushort(h);
    const __hip_bfloat16 l = __float2bfloat16(v[j] - __bfloat162float(h));
    lo[j] = (short)__bfloat16_as_ushort(l);
  }
}

// =====================================================================
// Kernel 1: block = (batch, k-half). Projects ITS 100 key rows + the
// 16 query rows (MFMA split-bf16 3-product), stores Ek/Eq in LDS, then
// computes full-h scores for its k-half -> d_ws. 61KB LDS -> 2 blocks/CU.
// =====================================================================
__launch_bounds__(512)
__attribute__((amdgpu_waves_per_eu(4, 4)))
__global__ void proj_score(const float* __restrict__ queries,
                           const float* __restrict__ keys,
                           const float* __restrict__ Wq,
                           const float* __restrict__ bq,
                           const float* __restrict__ Wk,
                           const float* __restrict__ bk,
                           const float* __restrict__ Wv,
                           float* __restrict__ ps) {
  __shared__ float skh[kHK * kS];   // Ek = exp2(kC2*kh), 100 rows  (52.8 KB)
  __shared__ float sqh[kNQ * kNH];  // Eq                           ( 8.2 KB)

  const int tid  = threadIdx.x;
  const int b    = blockIdx.x >> 1;
  const int half = blockIdx.x & 1;   // k-half: rows half*100 .. +99
  const int lane = tid & 63;
  const int wave = __builtin_amdgcn_readfirstlane(tid >> 6);  // 0..7
  const int l15  = lane & 15;
  const int q16  = lane >> 4;
  const int hbase = 8 * l15;

  const float* kb = keys + ((size_t)b * kNK + half * kHK) * kDK;  // this half's rows
  const float* qb = queries + (size_t)b * kNQ * kDK;

  // ---- projection: wave w = col-tile w (cols w*16..+15); 7 row-tiles + q-tile ----
  {
    const int col = wave * 16 + l15;
    const int kj0 = q16 * 8;

    short8 bh[2], bl[2];  // Wk col-slice fragments, once per wave
#pragma unroll
    for (int p = 0; p < 2; ++p) {
      float4 v0, v1;
      v0.x = Wk[(p * 32 + kj0 + 0) * kNH + col];
      v0.y = Wk[(p * 32 + kj0 + 1) * kNH + col];
      v0.z = Wk[(p * 32 + kj0 + 2) * kNH + col];
      v0.w = Wk[(p * 32 + kj0 + 3) * kNH + col];
      v1.x = Wk[(p * 32 + kj0 + 4) * kNH + col];
      v1.y = Wk[(p * 32 + kj0 + 5) * kNH + col];
      v1.z = Wk[(p * 32 + kj0 + 6) * kNH + col];
      v1.w = Wk[(p * 32 + kj0 + 7) * kNH + col];
      split8(v0, v1, bh[p], bl[p]);
    }
    const float bkc = bk[col];

    for (int tr = 0; tr < 7; ++tr) {   // rows 0..99 local (tile 6 partially masked)
      f32x4 acc = {0.f, 0.f, 0.f, 0.f};
      const int row = tr * 16 + l15;
      const bool ok = row < kHK;
#pragma unroll
      for (int p = 0; p < 2; ++p) {
        float4 a0 = {0.f, 0.f, 0.f, 0.f}, a1 = {0.f, 0.f, 0.f, 0.f};
        if (ok) {
          const float* ap = kb + (size_t)row * kDK + p * 32 + kj0;
          a0 = *reinterpret_cast<const float4*>(ap);
          a1 = *reinterpret_cast<const float4*>(ap + 4);
        }
        short8 ah, al;
        split8(a0, a1, ah, al);
        acc = __builtin_amdgcn_mfma_f32_16x16x32_bf16(al, bh[p], acc, 0, 0, 0);
        acc = __builtin_amdgcn_mfma_f32_16x16x32_bf16(ah, bl[p], acc, 0, 0, 0);
        acc = __builtin_amdgcn_mfma_f32_16x16x32_bf16(ah, bh[p], acc, 0, 0, 0);
      }
#pragma unroll
      for (int r = 0; r < 4; ++r) {
        const int rr = tr * 16 + q16 * 4 + r;  // C row = (lane>>4)*4 + reg
        if (rr < kHK) skh[rr * kS + col] = exp2_hw(kC2 * (acc[r] + bkc));
      }
    }

    // query tile (16 rows) for this wave's col-tile
    {
      short8 qbh[2], qbl[2];
#pragma unroll
      for (int p = 0; p < 2; ++p) {
        float4 v0, v1;
        v0.x = Wq[(p * 32 + kj0 + 0) * kNH + col];
        v0.y = Wq[(p * 32 + kj0 + 1) * kNH + col];
        v0.z = Wq[(p * 32 + kj0 + 2) * kNH + col];
        v0.w = Wq[(p * 32 + kj0 + 3) * kNH + col];
        v1.x = Wq[(p * 32 + kj0 + 4) * kNH + col];
        v1.y = Wq[(p * 32 + kj0 + 5) * kNH + col];
        v1.z = Wq[(p * 32 + kj0 + 6) * kNH + col];
        v1.w = Wq[(p * 32 + kj0 + 7) * kNH + col];
        split8(v0, v1, qbh[p], qbl[p]);
      }
      const float bqc = bq[col];
      f32x4 acc = {0.f, 0.f, 0.f, 0.f};
#pragma unroll
      for (int p = 0; p < 2; ++p) {
        const float* ap = qb + (size_t)l15 * kDK + p * 32 + kj0;
        const float4 a0 = *reinterpret_cast<const float4*>(ap);
        const float4 a1 = *reinterpret_cast<const float4*>(ap + 4);
        short8 ah, al;
        split8(a0, a1, ah, al);
        acc = __builtin_amdgcn_mfma_f32_16x16x32_bf16(al, qbh[p], acc, 0, 0, 0);
        acc = __builtin_amdgcn_mfma_f32_16x16x32_bf16(ah, qbl[p], acc, 0, 0, 0);
        acc = __builtin_amdgcn_mfma_f32_16x16x32_bf16(ah, qbh[p], acc, 0, 0, 0);
      }
#pragma unroll
      for (int r = 0; r < 4; ++r)
        sqh[(q16 * 4 + r) * kNH + col] = exp2_hw(kC2 * (acc[r] + bqc));
    }
  }

  // per-lane Wv slice
  float wv2[8];
  {
    const float4 wva = *reinterpret_cast<const float4*>(&Wv[hbase]);
    const float4 wvb = *reinterpret_cast<const float4*>(&Wv[hbase + 4]);
    wv2[0] = -2.0f * wva.x; wv2[1] = -2.0f * wva.y;
    wv2[2] = -2.0f * wva.z; wv2[3] = -2.0f * wva.w;
    wv2[4] = -2.0f * wvb.x; wv2[5] = -2.0f * wvb.y;
    wv2[6] = -2.0f * wvb.z; wv2[7] = -2.0f * wvb.w;
  }

  __syncthreads();  // Ek/Eq visible (the only barrier)

  // ---- scores: wave (qg,kg) -> queries 4qg..4qg+3, local k = 8i + 4kg + q16 ----
  const int qg = wave >> 1;  // 0..3
  const int kg = wave & 1;   // 0..1
  float qreg[4][8];
#pragma unroll
  for (int qi = 0; qi < 4; ++qi) {
    const float4 qa  = *reinterpret_cast<const float4*>(&sqh[(4 * qg + qi) * kNH + hbase]);
    const float4 qb4 = *reinterpret_cast<const float4*>(&sqh[(4 * qg + qi) * kNH + hbase + 4]);
    qreg[qi][0] = qa.x;  qreg[qi][1] = qa.y;  qreg[qi][2] = qa.z;  qreg[qi][3] = qa.w;
    qreg[qi][4] = qb4.x; qreg[qi][5] = qb4.y; qreg[qi][6] = qb4.z; qreg[qi][7] = qb4.w;
  }
#pragma unroll
  for (int qi = 0; qi < 4; ++qi)
#pragma unroll
    for (int m = 0; m < 8; ++m) asm volatile("" : "+v"(qreg[qi][m]));  // keep resident

  float* pw = ps + (size_t)b * kNQ * kNK + half * kHK;  // + q*kNK + klocal
  {
    auto score_k = [&](int k) {  // k local < 100
      const float* krow = &skh[k * kS + hbase];
      const float4 ka  = *reinterpret_cast<const float4*>(krow);
      const float4 kb4 = *reinterpret_cast<const float4*>(krow + 4);
#pragma unroll
      for (int qi = 0; qi < 4; ++qi) {
        const float e0 = qreg[qi][0] * ka.x;
        const float e1 = qreg[qi][1] * ka.y;
        const float e2 = qreg[qi][2] * ka.z;
        const float e3 = qreg[qi][3] * ka.w;
        const float e4 = qreg[qi][4] * kb4.x;
        const float e5 = qreg[qi][5] * kb4.y;
        const float e6 = qreg[qi][6] * kb4.z;
        const float e7 = qreg[qi][7] * kb4.w;
        const float r0 = __builtin_amdgcn_rcpf(1.0f + e0);
        const float r1 = __builtin_amdgcn_rcpf(1.0f + e1);
        const float r2 = __builtin_amdgcn_rcpf(1.0f + e2);
        const float r3 = __builtin_amdgcn_rcpf(1.0f + e3);
        const float r4 = __builtin_amdgcn_rcpf(1.0f + e4);
        const float r5 = __builtin_amdgcn_rcpf(1.0f + e5);
        const float r6 = __builtin_amdgcn_rcpf(1.0f + e6);
        const float r7 = __builtin_amdgcn_rcpf(1.0f + e7);
        float acc0 = wv2[0] * r0;
        acc0 = fmaf(wv2[1], r1, acc0);
        acc0 = fmaf(wv2[2], r2, acc0);
        acc0 = fmaf(wv2[3], r3, acc0);
        float acc1 = wv2[4] * r4;
        acc1 = fmaf(wv2[5], r5, acc1);
        acc1 = fmaf(wv2[6], r6, acc1);
        acc1 = fmaf(wv2[7], r7, acc1);
        float acc = acc0 + acc1;
        acc = dpp_add<0xB1>(acc);   // xor 1
        acc = dpp_add<0x4E>(acc);   // xor 2
        acc = dpp_add<0x141>(acc);  // row_half_mirror (8-fold)
        acc = dpp_add<0x140>(acc);  // row_mirror (16-fold)
        if (l15 == 0) pw[(4 * qg + qi) * kNK + k] = acc;
      }
    };
    for (int i = 0; i < 12; ++i) score_k(8 * i + 4 * kg + q16);
    if (kg == 0) score_k(96 + q16);  // tail k=96..99
  }
}

// =====================================================================
// Kernel 2: block = (batch, q-half of 8). mask -> softmax -> out_w;
// split-k GEMV -> out_attn. 15KB LDS, 512 thr -> 2 blocks/CU.
// =====================================================================
__launch_bounds__(512)
__global__ void softmax_gemv(const float* __restrict__ keys,
                             const float* __restrict__ masks,
                             const float* __restrict__ ps,
                             float* __restrict__ out_attn,
                             float* __restrict__ out_w) {
  __shared__ float sw[8 * kNK];      // weights, 8 local rows (6.4 KB)
  __shared__ float pk[8 * 4 * kDK];  // GEMV partials (8 KB)

  const int tid  = threadIdx.x;
  const int b    = blockIdx.x >> 1;
  const int qh2  = blockIdx.x & 1;
  const int lane = tid & 63;
  const int wave = __builtin_amdgcn_readfirstlane(tid >> 6);  // 0..7 = local row
  const int q    = qh2 * 8 + wave;                            // global query row

  const float* kbase = keys + (size_t)b * kNK * kDK;

  // ---- mask + softmax (wave owns one query row) ----
  {
    const float* p    = ps    + ((size_t)b * kNQ + q) * kNK;
    const float* mrow = masks + ((size_t)b * kNQ + q) * kNK;
    const bool tail = lane < (kNK - 192);
    float v0 = fmaf(mrow[lane],       kNeg, p[lane]);
    float v1 = fmaf(mrow[lane + 64],  kNeg, p[lane + 64]);
    float v2 = fmaf(mrow[lane + 128], kNeg, p[lane + 128]);
    float v3 = tail ? fmaf(mrow[lane + 192], kNeg, p[lane + 192]) : -1e30f;
    float m = fmaxf(fmaxf(v0, v1), fmaxf(v2, v3));
#pragma unroll
    for (int off = 32; off > 0; off >>= 1) m = fmaxf(m, __shfl_xor(m, off, 64));
    const float e0 = __expf(v0 - m);
    const float e1 = __expf(v1 - m);
    const float e2 = __expf(v2 - m);
    const float e3 = tail ? __expf(v3 - m) : 0.f;
    float sum = (e0 + e1) + (e2 + e3);
#pragma unroll
    for (int off = 32; off > 0; off >>= 1) sum += __shfl_xor(sum, off, 64);
    const float rs = __builtin_amdgcn_rcpf(sum);
    float* og  = out_w + ((size_t)b * kNQ + q) * kNK;
    float* swr = &sw[wave * kNK];
    const float w0 = e0 * rs, w1 = e1 * rs, w2 = e2 * rs, w3 = e3 * rs;
    swr[lane]       = w0;  og[lane]       = w0;
    swr[lane + 64]  = w1;  og[lane + 64]  = w1;
    swr[lane + 128] = w2;  og[lane + 128] = w2;
    if (tail) { swr[lane + 192] = w3; og[lane + 192] = w3; }
  }
  __syncthreads();

  // ---- split-k GEMV: wave (qg,kg) -> local rows 4qg..4qg+3, k-range kg ----
  {
    const int qg = wave >> 2;  // 0..1
    const int kg = wave & 3;   // 0..3
    const int kstart = 52 * kg;
    const int kend = (kg == 3) ? kNK : (kstart + 52);
    const float* kb2 = kbase + lane;  // d = lane
    float acc[4] = {0.f, 0.f, 0.f, 0.f};
    for (int k0 = kstart; k0 < kend; k0 += 4) {
      const float kv0 = kb2[(size_t)(k0 + 0) * kDK];
      const float kv1 = kb2[(size_t)(k0 + 1) * kDK];
      const float kv2 = kb2[(size_t)(k0 + 2) * kDK];
      const float kv3 = kb2[(size_t)(k0 + 3) * kDK];
#pragma unroll
      for (int qi = 0; qi < 4; ++qi) {
        const float4 wq = *reinterpret_cast<const float4*>(&sw[(4 * qg + qi) * kNK + k0]);
        acc[qi] = fmaf(wq.x, kv0, acc[qi]);
        acc[qi] = fmaf(wq.y, kv1, acc[qi]);
        acc[qi] = fmaf(wq.z, kv2, acc[qi]);
        acc[qi] = fmaf(wq.w, kv3, acc[qi]);
      }
    }
#pragma unroll
    for (int qi = 0; qi < 4; ++qi)
      pk[((4 * qg + qi) * 4 + kg) * kDK + lane] = acc[qi];
  }
  __syncthreads();

  // ---- combine: wave w sums 4 partials of its local row ----
  {
    const float r = pk[(wave * 4 + 0) * kDK + lane] + pk[(wave * 4 + 1) * kDK + lane] +
                    pk[(wave * 4 + 2) * kDK + lane] + pk[(wave * 4 + 3) * kDK + lane];
    out_attn[((size_t)b * kNQ + q) * kDK + lane] = r;
  }
}

// =====================================================================
// Fallback monolith (R6) — used only if ws_size is too small.
// =====================================================================
constexpr int kThreads = 1024;
constexpr int kKhFloats = kNK * kS;
constexpr int kScFloats = kNQ * kNK;
constexpr int kQhFloats = kNQ * kNH;
constexpr size_t kSmemBytes =
    (size_t)(kKhFloats + kScFloats + kQhFloats) * sizeof(float);

__launch_bounds__(kThreads)
__attribute__((amdgpu_waves_per_eu(4, 4)))
__global__ void bahdanau_fused(const float* __restrict__ queries,
                               const float* __restrict__ keys,
                               const float* __restrict__ masks,
                               const float* __restrict__ Wq,
                               const float* __restrict__ bq,
                               const float* __restrict__ Wk,
                               const float* __restrict__ bk,
                               const float* __restrict__ Wv,
                               float* __restrict__ out_attn,
                               float* __restrict__ out_w) {
  extern __shared__ __align__(16) float smem[];
  float* skh2 = smem;
  float* ssc = smem + kKhFloats;
  float* sqh2 = smem + kKhFloats + kScFloats;

  const int tid  = threadIdx.x;
  const int b    = blockIdx.x;
  const int lane = tid & 63;
  const int wave = __builtin_amdgcn_readfirstlane(tid >> 6);
  const int l15  = lane & 15;
  const int q16  = lane >> 4;
  const int hbase = 8 * l15;

  const float* kb = keys + (size_t)b * kNK * kDK;
  const float* qb = queries + (size_t)b * kNQ * kDK;

  {
    const int tc  = wave >> 1;
    const int odd = wave & 1;
    const int col = tc * 16 + l15;
    const int kj0 = q16 * 8;

    short8 bh[2], bl[2];
#pragma unroll
    for (int p = 0; p < 2; ++p) {
      float4 v0, v1;
      v0.x = Wk[(p * 32 + kj0 + 0) * kNH + col];
      v0.y = Wk[(p * 32 + kj0 + 1) * kNH + col];
      v0.z = Wk[(p * 32 + kj0 + 2) * kNH + col];
      v0.w = Wk[(p * 32 + kj0 + 3) * kNH + col];
      v1.x = Wk[(p * 32 + kj0 + 4) * kNH + col];
      v1.y = Wk[(p * 32 + kj0 + 5) * kNH + col];
      v1.z = Wk[(p * 32 + kj0 + 6) * kNH + col];
      v1.w = Wk[(p * 32 + kj0 + 7) * kNH + col];
      split8(v0, v1, bh[p], bl[p]);
    }
    const float bkc = bk[col];
    const int trB = odd ? 7 : 0;
    const int trE = odd ? 13 : 7;
    for (int tr = trB; tr < trE; ++tr) {
      f32x4 acc = {0.f, 0.f, 0.f, 0.f};
      const int row = tr * 16 + l15;
      const bool ok = row < kNK;
#pragma unroll
      for (int p = 0; p < 2; ++p) {
        float4 a0 = {0.f, 0.f, 0.f, 0.f}, a1 = {0.f, 0.f, 0.f, 0.f};
        if (ok) {
          const float* ap = kb + (size_t)row * kDK + p * 32 + kj0;
          a0 = *reinterpret_cast<const float4*>(ap);
          a1 = *reinterpret_cast<const float4*>(ap + 4);
        }
        short8 ah, al;
        split8(a0, a1, ah, al);
        acc = __builtin_amdgcn_mfma_f32_16x16x32_bf16(al, bh[p], acc, 0, 0, 0);
        acc = __builtin_amdgcn_mfma_f32_16x16x32_bf16(ah, bl[p], acc, 0, 0, 0);
        acc = __builtin_amdgcn_mfma_f32_16x16x32_bf16(ah, bh[p], acc, 0, 0, 0);
      }
#pragma unroll
      for (int r = 0; r < 4; ++r) {
        const int rr = tr * 16 + q16 * 4 + r;
        if (rr < kNK) skh2[(size_t)rr * kS + col] = exp2_hw(kC2 * (acc[r] + bkc));
      }
    }
    if (odd) {
      short8 qbh[2], qbl[2];
#pragma unroll
      for (int p = 0; p < 2; ++p) {
        float4 v0, v1;
        v0.x = Wq[(p * 32 + kj0 + 0) * kNH + col];
        v0.y = Wq[(p * 32 + kj0 + 1) * kNH + col];
        v0.z = Wq[(p * 32 + kj0 + 2) * kNH + col];
        v0.w = Wq[(p * 32 + kj0 + 3) * kNH + col];
        v1.x = Wq[(p * 32 + kj0 + 4) * kNH + col];
        v1.y = Wq[(p * 32 + kj0 + 5) * kNH + col];
        v1.z = Wq[(p * 32 + kj0 + 6) * kNH + col];
        v1.w = Wq[(p * 32 + kj0 + 7) * kNH + col];
        split8(v0, v1, qbh[p], qbl[p]);
      }
      const float bqc = bq[col];
      f32x4 acc = {0.f, 0.f, 0.f, 0.f};
#pragma unroll
      for (int p = 0; p < 2; ++p) {
        const float* ap = qb + (size_t)l15 * kDK + p * 32 + kj0;
        const float4 a0 = *reinterpret_cast<const float4*>(ap);
        const float4 a1 = *reinterpret_cast<const float4*>(ap + 4);
        short8 ah, al;
        split8(a0, a1, ah, al);
        acc = __builtin_amdgcn_mfma_f32_16x16x32_bf16(al, qbh[p], acc, 0, 0, 0);
        acc = __builtin_amdgcn_mfma_f32_16x16x32_bf16(ah, qbl[p], acc, 0, 0, 0);
        acc = __builtin_amdgcn_mfma_f32_16x16x32_bf16(ah, qbh[p], acc, 0, 0, 0);
      }
#pragma unroll
      for (int r = 0; r < 4; ++r)
        sqh2[(size_t)(q16 * 4 + r) * kNH + col] = exp2_hw(kC2 * (acc[r] + bqc));
    }
  }

  float wv2[8];
  {
    const float4 wva = *reinterpret_cast<const float4*>(&Wv[hbase]);
    const float4 wvb = *reinterpret_cast<const float4*>(&Wv[hbase + 4]);
    wv2[0] = -2.0f * wva.x; wv2[1] = -2.0f * wva.y;
    wv2[2] = -2.0f * wva.z; wv2[3] = -2.0f * wva.w;
    wv2[4] = -2.0f * wvb.x; wv2[5] = -2.0f * wvb.y;
    wv2[6] = -2.0f * wvb.z; wv2[7] = -2.0f * wvb.w;
  }

  __syncthreads();

  const int qg = wave >> 2;
  const int kg = wave & 3;
  float qreg[4][8];
#pragma unroll
  for (int qi = 0; qi < 4; ++qi) {
    const float4 qa  = *reinterpret_cast<const float4*>(&sqh2[(4 * qg + qi) * kNH + hbase]);
    const float4 qb4 = *reinterpret_cast<const float4*>(&sqh2[(4 * qg + qi) * kNH + hbase + 4]);
    qreg[qi][0] = qa.x;  qreg[qi][1] = qa.y;  qreg[qi][2] = qa.z;  qreg[qi][3] = qa.w;
    qreg[qi][4] = qb4.x; qreg[qi][5] = qb4.y; qreg[qi][6] = qb4.z; qreg[qi][7] = qb4.w;
  }

  {
    auto score_k = [&](int k) {
      const float* krow = &skh2[(size_t)k * kS + hbase];
      const float4 ka  = *reinterpret_cast<const float4*>(krow);
      const float4 kb4 = *reinterpret_cast<const float4*>(krow + 4);
#pragma unroll
      for (int qi = 0; qi < 4; ++qi) {
        const float e0 = qreg[qi][0] * ka.x;
        const float e1 = qreg[qi][1] * ka.y;
        const float e2 = qreg[qi][2] * ka.z;
        const float e3 = qreg[qi][3] * ka.w;
        const float e4 = qreg[qi][4] * kb4.x;
        const float e5 = qreg[qi][5] * kb4.y;
        const float e6 = qreg[qi][6] * kb4.z;
        const float e7 = qreg[qi][7] * kb4.w;
        const float r0 = __builtin_amdgcn_rcpf(1.0f + e0);
        const float r1 = __builtin_amdgcn_rcpf(1.0f + e1);
        const float r2 = __builtin_amdgcn_rcpf(1.0f + e2);
        const float r3 = __builtin_amdgcn_rcpf(1.0f + e3);
        const float r4 = __builtin_amdgcn_rcpf(1.0f + e4);
        const float r5 = __builtin_amdgcn_rcpf(1.0f + e5);
        const float r6 = __builtin_amdgcn_rcpf(1.0f + e6);
        const float r7 = __builtin_amdgcn_rcpf(1.0f + e7);
        float acc0 = wv2[0] * r0;
        acc0 = fmaf(wv2[1], r1, acc0);
        acc0 = fmaf(wv2[2], r2, acc0);
        acc0 = fmaf(wv2[3], r3, acc0);
        float acc1 = wv2[4] * r4;
        acc1 = fmaf(wv2[5], r5, acc1);
        acc1 = fmaf(wv2[6], r6, acc1);
        acc1 = fmaf(wv2[7], r7, acc1);
        float acc = acc0 + acc1;
        acc = dpp_add<0xB1>(acc);
        acc = dpp_add<0x4E>(acc);
        acc = dpp_add<0x141>(acc);
        acc = dpp_add<0x140>(acc);
        if (l15 == 0) ssc[(4 * qg + qi) * kNK + k] = acc;
      }
    };
    for (int i = 0; i < 12; ++i) score_k(16 * i + 4 * kg + q16);
    if (kg < 2) score_k(192 + 4 * kg + q16);
  }

  const float* mrow = masks + ((size_t)b * kNQ + wave) * kNK;
  const bool tail = lane < (kNK - 192);
  const float mm0 = mrow[lane];
  const float mm1 = mrow[lane + 64];
  const float mm2 = mrow[lane + 128];
  const float mm3 = tail ? mrow[lane + 192] : 0.0f;

  __syncthreads();

  {
    const float* sr = &ssc[wave * kNK];
    float v0 = fmaf(mm0, kNeg, sr[lane]);
    float v1 = fmaf(mm1, kNeg, sr[lane + 64]);
    float v2 = fmaf(mm2, kNeg, sr[lane + 128]);
    float v3 = tail ? fmaf(mm3, kNeg, sr[lane + 192]) : -1e30f;
    float m = fmaxf(fmaxf(v0, v1), fmaxf(v2, v3));
#pragma unroll
    for (int off = 32; off > 0; off >>= 1) m = fmaxf(m, __shfl_xor(m, off, 64));
    const float e0 = __expf(v0 - m);
    const float e1 = __expf(v1 - m);
    const float e2 = __expf(v2 - m);
    const float e3 = tail ? __expf(v3 - m) : 0.f;
    float sum = (e0 + e1) + (e2 + e3);
#pragma unroll
    for (int off = 32; off > 0; off >>= 1) sum += __shfl_xor(sum, off, 64);
    const float rs = __builtin_amdgcn_rcpf(sum);
    float* og = out_w + ((size_t)b * kNQ + wave) * kNK;
    float* swr = &ssc[wave * kNK];
    const float w0 = e0 * rs, w1 = e1 * rs, w2 = e2 * rs, w3 = e3 * rs;
    swr[lane]       = w0;  og[lane]       = w0;
    swr[lane + 64]  = w1;  og[lane + 64]  = w1;
    swr[lane + 128] = w2;  og[lane + 128] = w2;
    if (tail) { swr[lane + 192] = w3; og[lane + 192] = w3; }
  }
  __syncthreads();

  {
    float* pk2 = skh2;
    const int kstart = 52 * kg;
    const int kend = (kg == 3) ? kNK : (kstart + 52);
    const float* kb2 = kb + lane;
    float acc[4] = {0.f, 0.f, 0.f, 0.f};
    for (int k0 = kstart; k0 < kend; k0 += 4) {
      const float kv0 = kb2[(size_t)(k0 + 0) * kDK];
      const float kv1 = kb2[(size_t)(k0 + 1) * kDK];
      const float kv2 = kb2[(size_t)(k0 + 2) * kDK];
      const float kv3 = kb2[(size_t)(k0 + 3) * kDK];
#pragma unroll
      for (int qi = 0; qi < 4; ++qi) {
        const float4 wq = *reinterpret_cast<const float4*>(&ssc[(4 * qg + qi) * kNK + k0]);
        acc[qi] = fmaf(wq.x, kv0, acc[qi]);
        acc[qi] = fmaf(wq.y, kv1, acc[qi]);
        acc[qi] = fmaf(wq.z, kv2, acc[qi]);
        acc[qi] = fmaf(wq.w, kv3, acc[qi]);
      }
    }
#pragma unroll
    for (int qi = 0; qi < 4; ++qi)
      pk2[((4 * qg + qi) * 4 + kg) * kDK + lane] = acc[qi];
  }
  __syncthreads();

  {
    const float* pk2 = skh2;
    const float r = pk2[(wave * 4 + 0) * kDK + lane] + pk2[(wave * 4 + 1) * kDK + lane] +
                    pk2[(wave * 4 + 2) * kDK + lane] + pk2[(wave * 4 + 3) * kDK + lane];
    out_attn[((size_t)b * kNQ + wave) * kDK + lane] = r;
  }
}

}  // namespace

extern "C" void kernel_launch(void* const* d_in, const int* in_sizes, int n_in,
                              void* d_out, int out_size, void* d_ws, size_t ws_size,
                              hipStream_t stream) {
  const float* queries = (const float*)d_in[0];
  const float* keys    = (const float*)d_in[1];
  const float* masks   = (const float*)d_in[2];
  // d_in[3] = num_neg (unused)
  const float* Wq = (const float*)d_in[4];
  const float* bq = (const float*)d_in[5];
  const float* Wk = (const float*)d_in[6];
  const float* bk = (const float*)d_in[7];
  const float* Wv = (const float*)d_in[8];
  // d_in[9] = bv: softmax-invariant, dropped

  float* out_attn = (float*)d_out;                       // (B, NQ, 64)
  float* out_w    = out_attn + (size_t)kNB * kNQ * kDK;  // (B, NQ, 200, 1)

  if (ws_size >= kWsNeed) {
    float* ps = (float*)d_ws;  // (B, NQ, NK) full scores
    proj_score<<<kNB * 2, 512, 0, stream>>>(queries, keys, Wq, bq, Wk, bk, Wv, ps);
    softmax_gemv<<<kNB * 2, 512, 0, stream>>>(keys, masks, ps, out_attn, out_w);
  } else {
    hipFuncSetAttribute((const void*)bahdanau_fused,
                        hipFuncAttributeMaxDynamicSharedMemorySize, (int)kSmemBytes);
    bahdanau_fused<<<kNB, kThreads, kSmemBytes, stream>>>(queries, keys, masks, Wq, bq,
                                                          Wk, bk, Wv, out_attn, out_w);
  }
}